// Round 1
// baseline (475.317 us; speedup 1.0000x reference)
//
#include <hip/hip_runtime.h>
#include <hip/hip_bf16.h>

#define BB 16
#define NN 2048
#define FIN 256
#define FO 64

typedef __bf16 bf16x8 __attribute__((ext_vector_type(8)));
typedef float  f32x4  __attribute__((ext_vector_type(4)));
typedef int    i32x4  __attribute__((ext_vector_type(4)));

// ---------------- K0: tiny prep (1 block) ----------------
// Wt[o][k] = bf16(weight[k][o])  (B-frag friendly, 64x256)
// v_src[k] = sum_o W[k][o]*a_src[o], v_dst likewise (exact fp32 logits path)
__global__ void k0_prep(const float* __restrict__ weight, const float* __restrict__ w2,
                        __bf16* __restrict__ Wt, float* __restrict__ vsrc,
                        float* __restrict__ vdst) {
    int t = threadIdx.x;  // 256 threads
    for (int idx = t; idx < FIN * FO; idx += 256) {
        int k = idx >> 6, o = idx & 63;
        Wt[o * FIN + k] = (__bf16)weight[idx];  // idx = k*64+o
    }
    // t == k
    float a = 0.f, d = 0.f;
    for (int o = 0; o < FO; ++o) {
        float wv = weight[t * FO + o];
        a += wv * w2[o];
        d += wv * w2[FO + o];
    }
    vsrc[t] = a;
    vdst[t] = d;
}

// ---------------- K1: h GEMM (MFMA bf16) + exact fp32 s_src/s_dst ------------
// Computes hT[b][o][n] = bf16( (x@W)[b][n][o] ) via D = Wt(A, o x k) * xT(B, k x n)
// wave = 16 rows; block = 4 waves = 64 rows; grid = 32768/64 = 512
__global__ __launch_bounds__(256) void k1_gemm(
    const float* __restrict__ x, const __bf16* __restrict__ Wt,
    const float* __restrict__ vsrc, const float* __restrict__ vdst,
    __bf16* __restrict__ hT, float* __restrict__ s_src, float* __restrict__ s_dst) {
    int lane = threadIdx.x & 63, w = threadIdx.x >> 6;
    int quad = lane >> 4, m = lane & 15;
    int Rbase = blockIdx.x * 64 + w * 16;
    int R = Rbase + m;  // this lane's x-row (B-operand n-index)
    const float* xr = x + (long)R * FIN;

    f32x4 acc[4] = {};
    float ps = 0.f, pd = 0.f;

#pragma unroll
    for (int k0 = 0; k0 < FIN; k0 += 32) {
        int kb = k0 + quad * 8;
        float4 x0 = *(const float4*)(xr + kb);
        float4 x1 = *(const float4*)(xr + kb + 4);
        float4 u0 = *(const float4*)(vsrc + kb);
        float4 u1 = *(const float4*)(vsrc + kb + 4);
        float4 t0 = *(const float4*)(vdst + kb);
        float4 t1 = *(const float4*)(vdst + kb + 4);
        ps += x0.x * u0.x + x0.y * u0.y + x0.z * u0.z + x0.w * u0.w +
              x1.x * u1.x + x1.y * u1.y + x1.z * u1.z + x1.w * u1.w;
        pd += x0.x * t0.x + x0.y * t0.y + x0.z * t0.z + x0.w * t0.w +
              x1.x * t1.x + x1.y * t1.y + x1.z * t1.z + x1.w * t1.w;
        bf16x8 bf = {(__bf16)x0.x, (__bf16)x0.y, (__bf16)x0.z, (__bf16)x0.w,
                     (__bf16)x1.x, (__bf16)x1.y, (__bf16)x1.z, (__bf16)x1.w};
#pragma unroll
        for (int ot = 0; ot < 4; ++ot) {
            bf16x8 af = *(const bf16x8*)(Wt + (ot * 16 + m) * FIN + kb);
            acc[ot] = __builtin_amdgcn_mfma_f32_16x16x32_bf16(af, bf, acc[ot], 0, 0, 0);
        }
    }
    // reduce fp32 logits across quads (lanes m, m+16, m+32, m+48 share row R)
    ps += __shfl_xor(ps, 16);
    ps += __shfl_xor(ps, 32);
    pd += __shfl_xor(pd, 16);
    pd += __shfl_xor(pd, 32);
    if (quad == 0) {
        s_src[R] = ps;
        s_dst[R] = pd;
    }
    // store hT: D layout col=lane&15 (-> row index n), row=quad*4+r (-> o index)
    int b = R >> 11;
    int nb = Rbase & (NN - 1);
#pragma unroll
    for (int ot = 0; ot < 4; ++ot) {
#pragma unroll
        for (int r = 0; r < 4; ++r) {
            int o = ot * 16 + quad * 4 + r;
            hT[((long)b * FO + o) * NN + nb + m] = (__bf16)acc[ot][r];
        }
    }
}

// ---------------- K2: fused masked-softmax attention + PV (the 268 MB kernel) --
// grid = 16 b * 32 itiles = 512 blocks; block = 4 waves; wave owns 16 i-rows.
// No __syncthreads anywhere: maxdst + l reductions are wave-shuffle only.
__global__ __launch_bounds__(256) void k2_attn(
    const int* __restrict__ adj, const float* __restrict__ s_src,
    const float* __restrict__ s_dst, const __bf16* __restrict__ hT,
    float* __restrict__ out) {
    int b = blockIdx.x >> 5;
    int i0 = (blockIdx.x & 31) << 6;
    int lane = threadIdx.x & 63, w = threadIdx.x >> 6;
    int quad = lane >> 4, m = lane & 15;
    int row = i0 + w * 16 + m;  // this lane's P-row (A-operand m-index)

    const float* sd = s_dst + b * NN;
    // wave-local max over s_dst[b][:]  (upper-bound stabilizer, j-independent)
    float mx = -3.0e38f;
    for (int j = lane; j < NN; j += 64) mx = fmaxf(mx, sd[j]);
#pragma unroll
    for (int off = 32; off >= 1; off >>= 1) mx = fmaxf(mx, __shfl_xor(mx, off));

    float ssrc = s_src[b * NN + row];
    float M = fmaxf(ssrc + mx, 0.f);

    const int* adjrow = adj + ((long)b * NN + row) * NN;
    const __bf16* hTb = hT + (long)b * FO * NN;

    f32x4 acc[4] = {};
    float lp = 0.f;

#pragma unroll 2
    for (int j0 = 0; j0 < NN; j0 += 32) {
        int jb = j0 + quad * 8;
        i32x4 a0 = __builtin_nontemporal_load((const i32x4*)(adjrow + jb));
        i32x4 a1 = __builtin_nontemporal_load((const i32x4*)(adjrow + jb) + 1);
        float4 d0 = *(const float4*)(sd + jb);
        float4 d1 = *(const float4*)(sd + jb + 4);

        float p0 = (a0.x > 0) ? __expf(fmaxf(ssrc + d0.x, 0.f) - M) : 0.f;
        float p1 = (a0.y > 0) ? __expf(fmaxf(ssrc + d0.y, 0.f) - M) : 0.f;
        float p2 = (a0.z > 0) ? __expf(fmaxf(ssrc + d0.z, 0.f) - M) : 0.f;
        float p3 = (a0.w > 0) ? __expf(fmaxf(ssrc + d0.w, 0.f) - M) : 0.f;
        float p4 = (a1.x > 0) ? __expf(fmaxf(ssrc + d1.x, 0.f) - M) : 0.f;
        float p5 = (a1.y > 0) ? __expf(fmaxf(ssrc + d1.y, 0.f) - M) : 0.f;
        float p6 = (a1.z > 0) ? __expf(fmaxf(ssrc + d1.z, 0.f) - M) : 0.f;
        float p7 = (a1.w > 0) ? __expf(fmaxf(ssrc + d1.w, 0.f) - M) : 0.f;
        lp += ((p0 + p1) + (p2 + p3)) + ((p4 + p5) + (p6 + p7));

        bf16x8 af = {(__bf16)p0, (__bf16)p1, (__bf16)p2, (__bf16)p3,
                     (__bf16)p4, (__bf16)p5, (__bf16)p6, (__bf16)p7};
        const __bf16* hb = hTb + jb;
#pragma unroll
        for (int ot = 0; ot < 4; ++ot) {
            bf16x8 bf = *(const bf16x8*)(hb + (ot * 16 + m) * NN);
            acc[ot] = __builtin_amdgcn_mfma_f32_16x16x32_bf16(af, bf, acc[ot], 0, 0, 0);
        }
    }

    // l_i: reduce across quads (lanes sharing m); every lane then holds l(row m)
    lp += __shfl_xor(lp, 16);
    lp += __shfl_xor(lp, 32);

    // epilogue: D layout col=lane&15 (o), row=quad*4+r (i-local)
    float* outp = out + ((long)b * NN + i0 + w * 16) * FO;
#pragma unroll
    for (int r = 0; r < 4; ++r) {
        int orow = quad * 4 + r;
        float lr = __shfl(lp, orow);  // lane 'orow' holds l for i-local = orow
        float inv = 1.0f / lr;
#pragma unroll
        for (int ot = 0; ot < 4; ++ot) {
            outp[(long)orow * FO + ot * 16 + m] = acc[ot][r] * inv;
        }
    }
}

extern "C" void kernel_launch(void* const* d_in, const int* in_sizes, int n_in,
                              void* d_out, int out_size, void* d_ws, size_t ws_size,
                              hipStream_t stream) {
    const float* x      = (const float*)d_in[0];
    const int*   adj    = (const int*)d_in[1];
    const float* weight = (const float*)d_in[2];
    const float* w2     = (const float*)d_in[3];
    float* out = (float*)d_out;

    char* ws = (char*)d_ws;
    __bf16* hT   = (__bf16*)ws;                               // 16*64*2048*2 = 4 MB
    float* s_src = (float*)(ws + 4194304);                    // 128 KB
    float* s_dst = (float*)(ws + 4194304 + 131072);           // 128 KB
    float* vsrc  = (float*)(ws + 4194304 + 262144);           // 1 KB
    float* vdst  = (float*)(ws + 4194304 + 262144 + 1024);    // 1 KB
    __bf16* Wt   = (__bf16*)(ws + 4194304 + 262144 + 2048);   // 32 KB

    k0_prep<<<1, 256, 0, stream>>>(weight, w2, Wt, vsrc, vdst);
    k1_gemm<<<512, 256, 0, stream>>>(x, Wt, vsrc, vdst, hT, s_src, s_dst);
    k2_attn<<<512, 256, 0, stream>>>(adj, s_src, s_dst, hT, out);
}